// Round 1
// baseline (420.315 us; speedup 1.0000x reference)
//
#include <hip/hip_runtime.h>

// GeneralizedHamiltonianDynamics: bf16 MFMA pipeline
// B=32768, DIN=64, HID=1024
// K0: pack weights bf16 (B-pack layout Bp[n][k])
// K1: h1 = tanh(z@W1+b1)            -> ws (bf16)
// K2: gpre2 = W3*(1-tanh^2(h1@W2+b2)) -> ws (bf16)
// K3: gpre1 = (gpre2@W2^T)*(1-h1^2) -> in-place over h1 buffer (bf16)
// K4: out = symplectic(gpre1@W1^T) + tanh(z@Wf1+bf1)@Wf2 + bf2  (fp32)

typedef __attribute__((ext_vector_type(8))) short s16x8;
typedef __attribute__((ext_vector_type(4))) float f32x4;
typedef unsigned short u16;

#define DEVFN static __device__ __forceinline__

constexpr int DIN = 64;
constexpr int HID = 1024;

DEVFN u16 f2bf(float f) {
  unsigned u = __builtin_bit_cast(unsigned, f);
  u += 0x7fffu + ((u >> 16) & 1u);   // round-to-nearest-even
  return (u16)(u >> 16);
}
DEVFN float bf2f(u16 h) {
  unsigned u = ((unsigned)h) << 16;
  return __builtin_bit_cast(float, u);
}
DEVFN float fast_tanh(float x) {
  // tanh(x) = 1 - 2/(exp(2x)+1); exp via hw exp2
  float e = __builtin_amdgcn_exp2f(x * 2.8853900817779268f);
  return 1.0f - 2.0f * __builtin_amdgcn_rcpf(e + 1.0f);
}
DEVFN f32x4 mfma16(s16x8 a, s16x8 b, f32x4 c) {
  return __builtin_amdgcn_mfma_f32_16x16x32_bf16(a, b, c, 0, 0, 0);
}

#define GLOAD16(g, l) __builtin_amdgcn_global_load_lds( \
    (const __attribute__((address_space(1))) unsigned int*)(const void*)(g), \
    (__attribute__((address_space(3))) unsigned int*)(void*)(l), 16, 0, 0)

// ---------------- K0: weight prep ----------------
// W1p [1024][64]  = W1^T   (B-pack for z@W1)
// Wf1p[1024][64]  = Wf1^T  (B-pack for z@Wf1)
// W2tp[1024][1024]= W2^T   (B-pack for h1@W2)
// W2c [1024][1024]= W2     (B-pack for gpre2@W2^T)
// W1c [64][1024]  = W1     (B-pack for gpre1@W1^T)
// Wf2p[64][1024]  = Wf2^T  (B-pack for f1@Wf2)
__global__ __launch_bounds__(256) void k0_prep(
    const float* W1, const float* W2, const float* Wf1, const float* Wf2,
    u16* W1p, u16* Wf1p, u16* W2tp, u16* W2c, u16* W1c, u16* Wf2p) {
  int id = blockIdx.x * 256 + threadIdx.x;  // grid covers 1048576
  {
    int n = id >> 10, k = id & 1023;
    W2tp[id] = f2bf(W2[k * HID + n]);
    W2c[id]  = f2bf(W2[id]);
  }
  if (id < 65536) {
    int n = id >> 6, k = id & 63;          // n<1024, k<64
    W1p[id]  = f2bf(W1[k * HID + n]);
    Wf1p[id] = f2bf(Wf1[k * HID + n]);
    W1c[id]  = f2bf(W1[id]);
    int n2 = id >> 10, k2 = id & 1023;     // n2<64, k2<1024
    Wf2p[id] = f2bf(Wf2[k2 * DIN + n2]);
  }
}

// ---------------- K1: h1 = tanh(z@W1 + b1) ----------------
// grid: (32768/64) x (1024/128) = 4096 blocks of 256
__global__ __launch_bounds__(256) void k1_h1(const float* z, const u16* W1p,
                                             const float* b1, u16* h1) {
  __shared__ __align__(16) u16 zl[64 * 72];  // padded stride 72 (2-way banks)
  const int tid = threadIdx.x;
  const int lane = tid & 63, w = tid >> 6;
  const int nb = blockIdx.x & 7, mb = blockIdx.x >> 3;
  const size_t m0 = (size_t)mb * 64;
  const int n0 = nb * 128;
  // stage z tile [64][64] fp32 -> bf16 LDS
#pragma unroll
  for (int c = 0; c < 4; ++c) {
    int i4 = c * 256 + tid;                 // float4 index 0..1023
    int row = i4 >> 4, col4 = (i4 & 15) * 4;
    f32x4 v = *reinterpret_cast<const f32x4*>(z + (m0 + row) * DIN + col4);
    u16* d = zl + row * 72 + col4;
    d[0] = f2bf(v[0]); d[1] = f2bf(v[1]); d[2] = f2bf(v[2]); d[3] = f2bf(v[3]);
  }
  __syncthreads();
  f32x4 acc[8] = {};
#pragma unroll
  for (int kk = 0; kk < 2; ++kk) {
    const int karr = kk * 32 + ((lane >> 4) << 3);
    s16x8 a = *reinterpret_cast<const s16x8*>(zl + (16 * w + (lane & 15)) * 72 + karr);
#pragma unroll
    for (int fn = 0; fn < 8; ++fn) {
      int n = n0 + fn * 16 + (lane & 15);
      s16x8 b = *reinterpret_cast<const s16x8*>(W1p + (size_t)n * 64 + karr);
      acc[fn] = mfma16(a, b, acc[fn]);
    }
  }
#pragma unroll
  for (int fn = 0; fn < 8; ++fn) {
    int n = n0 + fn * 16 + (lane & 15);
    float bias = b1[n];
#pragma unroll
    for (int j = 0; j < 4; ++j) {
      size_t m = m0 + 16 * w + ((lane >> 4) << 2) + j;
      h1[m * HID + n] = f2bf(fast_tanh(acc[fn][j] + bias));
    }
  }
}

// ---------------- K2/K3: big GEMMs (m97-style 128x128 tile, BK=64) ----------
// MODE 0: out = bf16( W3[n] * (1 - tanh^2(A@Bp^T + b2[n])) )    (A=h1, Bp=W2^T-pack)
// MODE 1: out = bf16( (A@Bp^T) * (1 - h1[m][n]^2) )  in-place   (A=gpre2, Bp=W2-pack)
template <int MODE>
__global__ __launch_bounds__(256) void k23_gemm(const u16* A, const u16* Bp,
                                                const float* b2, const float* W3,
                                                const u16* h1in, u16* outb) {
  __shared__ __align__(16) u16 la[128 * 64];
  __shared__ __align__(16) u16 lb[128 * 64];
  const int tid = threadIdx.x;
  const int lane = tid & 63, w = tid >> 6;
  const int wr = w >> 1, wc = w & 1;
  const int nb = blockIdx.x & 7, mb = blockIdx.x >> 3;
  const size_t m0 = (size_t)mb * 128;
  const int n0 = nb * 128;
  f32x4 acc[4][4] = {};
  for (int kt = 0; kt < 16; ++kt) {
    const int k0 = kt * 64;
    __syncthreads();
#pragma unroll
    for (int c = 0; c < 4; ++c) {
      int idx = c * 256 + tid;
      int row = idx >> 3, k8 = (idx & 7) << 3;
      GLOAD16(A + (m0 + row) * 1024 + k0 + k8, la + idx * 8);
      GLOAD16(Bp + (size_t)(n0 + row) * 1024 + k0 + k8, lb + idx * 8);
    }
    __syncthreads();
#pragma unroll
    for (int kk = 0; kk < 2; ++kk) {
      const int karr = kk * 32 + ((lane >> 4) << 3);
      s16x8 a[4], b[4];
#pragma unroll
      for (int i = 0; i < 4; ++i)
        a[i] = *reinterpret_cast<const s16x8*>(la + (64 * wr + 16 * i + (lane & 15)) * 64 + karr);
#pragma unroll
      for (int i = 0; i < 4; ++i)
        b[i] = *reinterpret_cast<const s16x8*>(lb + (64 * wc + 16 * i + (lane & 15)) * 64 + karr);
#pragma unroll
      for (int i = 0; i < 4; ++i)
#pragma unroll
        for (int j = 0; j < 4; ++j)
          acc[i][j] = mfma16(a[i], b[j], acc[i][j]);
    }
  }
#pragma unroll
  for (int j = 0; j < 4; ++j) {
    int n = n0 + 64 * wc + 16 * j + (lane & 15);
    float b2v = 0.f, w3v = 0.f;
    if (MODE == 0) { b2v = b2[n]; w3v = W3[n]; }
#pragma unroll
    for (int i = 0; i < 4; ++i) {
#pragma unroll
      for (int r = 0; r < 4; ++r) {
        size_t m = m0 + 64 * wr + 16 * i + ((lane >> 4) << 2) + r;
        float v = acc[i][j][r];
        if (MODE == 0) {
          float t = fast_tanh(v + b2v);
          outb[m * 1024 + n] = f2bf(w3v * (1.f - t * t));
        } else {
          float h = bf2f(h1in[m * 1024 + n]);
          outb[m * 1024 + n] = f2bf(v * (1.f - h * h));
        }
      }
    }
  }
}

// ---------------- K4: final fused kernel ----------------
// out[m][n] = forcing + bf2[n] + sign * gradH[m][(n+32)%64]
// forcing computed chunk-wise: f1 = tanh(z@Wf1+bf1) (LDS), acc += f1@Wf2
// gradH = gpre1 @ W1^T  (gpre1 streamed from HBM via global_load_lds)
__global__ __launch_bounds__(256) void k4_final(
    const float* z, const u16* gp1, const u16* Wf1p, const u16* Wf2p,
    const u16* W1c, const float* bf1, const float* bf2, float* out) {
  __shared__ __align__(16) u16 zl[64 * 72];
  __shared__ __align__(16) u16 f1l[64 * 72];
  __shared__ __align__(16) u16 gl[64 * 64];
  const int tid = threadIdx.x;
  const int lane = tid & 63, w = tid >> 6;
  const size_t m0 = (size_t)blockIdx.x * 64;
  // stage z tile
#pragma unroll
  for (int c = 0; c < 4; ++c) {
    int i4 = c * 256 + tid;
    int row = i4 >> 4, col4 = (i4 & 15) * 4;
    f32x4 v = *reinterpret_cast<const f32x4*>(z + (m0 + row) * DIN + col4);
    u16* d = zl + row * 72 + col4;
    d[0] = f2bf(v[0]); d[1] = f2bf(v[1]); d[2] = f2bf(v[2]); d[3] = f2bf(v[3]);
  }
  __syncthreads();
  f32x4 facc[4] = {};
  f32x4 hacc[4] = {};
  for (int kc = 0; kc < 16; ++kc) {
    const int kbase = kc * 64;
    // forcing stage 1: f1 chunk (this wave's 16 rows), K=64 over z
    f32x4 pacc[4] = {};
#pragma unroll
    for (int kk = 0; kk < 2; ++kk) {
      const int karr = kk * 32 + ((lane >> 4) << 3);
      s16x8 a = *reinterpret_cast<const s16x8*>(zl + (16 * w + (lane & 15)) * 72 + karr);
#pragma unroll
      for (int fn = 0; fn < 4; ++fn) {
        int n = kbase + fn * 16 + (lane & 15);
        s16x8 b = *reinterpret_cast<const s16x8*>(Wf1p + (size_t)n * 64 + karr);
        pacc[fn] = mfma16(a, b, pacc[fn]);
      }
    }
#pragma unroll
    for (int fn = 0; fn < 4; ++fn) {
      int nloc = fn * 16 + (lane & 15);
      float bias = bf1[kbase + nloc];
#pragma unroll
      for (int j = 0; j < 4; ++j) {
        int r = 16 * w + ((lane >> 4) << 2) + j;
        f1l[r * 72 + nloc] = f2bf(fast_tanh(pacc[fn][j] + bias));
      }
    }
    // stage gpre1 chunk [64][64] (overlaps with forcing stage 2 below)
    __syncthreads();  // protect gl from previous iteration's readers
#pragma unroll
    for (int c = 0; c < 2; ++c) {
      int idx = c * 256 + tid;
      int row = idx >> 3, k8 = (idx & 7) << 3;
      GLOAD16(gp1 + (m0 + row) * 1024 + kbase + k8, gl + idx * 8);
    }
    // forcing stage 2: facc += f1 @ Wf2  (wave-local rows of f1l)
#pragma unroll
    for (int kk = 0; kk < 2; ++kk) {
      const int karr = kk * 32 + ((lane >> 4) << 3);
      s16x8 af = *reinterpret_cast<const s16x8*>(f1l + (16 * w + (lane & 15)) * 72 + karr);
#pragma unroll
      for (int fn = 0; fn < 4; ++fn) {
        int n = fn * 16 + (lane & 15);
        s16x8 b = *reinterpret_cast<const s16x8*>(Wf2p + (size_t)n * 1024 + kbase + karr);
        facc[fn] = mfma16(af, b, facc[fn]);
      }
    }
    __syncthreads();  // gl ready
    // gradH: hacc += gpre1_chunk @ W1^T
#pragma unroll
    for (int kk = 0; kk < 2; ++kk) {
      const int karr = kk * 32 + ((lane >> 4) << 3);
      s16x8 ag = *reinterpret_cast<const s16x8*>(gl + (16 * w + (lane & 15)) * 64 + karr);
#pragma unroll
      for (int fn = 0; fn < 4; ++fn) {
        int n = fn * 16 + (lane & 15);
        s16x8 b = *reinterpret_cast<const s16x8*>(W1c + (size_t)n * 1024 + kbase + karr);
        hacc[fn] = mfma16(ag, b, hacc[fn]);
      }
    }
  }
  // store: symplectic combine + forcing + bf2
#pragma unroll
  for (int fn = 0; fn < 4; ++fn) {
    int n = fn * 16 + (lane & 15);
    float bias = bf2[n];
    float sgn = (fn < 2) ? 1.f : -1.f;   // out[:, <32] = +gradH[:, +32]; out[:, >=32] = -gradH[:, -32]
#pragma unroll
    for (int j = 0; j < 4; ++j) {
      size_t m = m0 + 16 * w + ((lane >> 4) << 2) + j;
      out[m * DIN + n] = facc[fn][j] + bias + sgn * hacc[(fn + 2) & 3][j];
    }
  }
}

extern "C" void kernel_launch(void* const* d_in, const int* in_sizes, int n_in,
                              void* d_out, int out_size, void* d_ws, size_t ws_size,
                              hipStream_t stream) {
  const float* z   = (const float*)d_in[0];
  const float* W1  = (const float*)d_in[1];
  const float* b1  = (const float*)d_in[2];
  const float* W2  = (const float*)d_in[3];
  const float* b2  = (const float*)d_in[4];
  const float* W3  = (const float*)d_in[5];
  // d_in[6] = b3: gradient-free and not part of output -> unused
  const float* Wf1 = (const float*)d_in[7];
  const float* bf1 = (const float*)d_in[8];
  const float* Wf2 = (const float*)d_in[9];
  const float* bf2 = (const float*)d_in[10];

  char* ws = (char*)d_ws;
  u16* W1p  = (u16*)(ws + 0);          // 128KB
  u16* Wf1p = (u16*)(ws + 131072);     // 128KB
  u16* W2tp = (u16*)(ws + 262144);     // 2MB
  u16* W2c  = (u16*)(ws + 2359296);    // 2MB
  u16* W1c  = (u16*)(ws + 4456448);    // 128KB
  u16* Wf2p = (u16*)(ws + 4587520);    // 128KB
  u16* h1   = (u16*)(ws + 4718592);    // 64MB (becomes gpre1 in-place after K3)
  u16* gp2  = (u16*)(ws + 4718592 + 67108864);  // 64MB
  float* out = (float*)d_out;

  k0_prep<<<4096, 256, 0, stream>>>(W1, W2, Wf1, Wf2, W1p, Wf1p, W2tp, W2c, W1c, Wf2p);
  k1_h1<<<4096, 256, 0, stream>>>(z, W1p, b1, h1);
  k23_gemm<0><<<2048, 256, 0, stream>>>(h1, W2tp, b2, W3, nullptr, gp2);
  k23_gemm<1><<<2048, 256, 0, stream>>>(gp2, W2c, nullptr, nullptr, h1, h1);
  k4_final<<<512, 256, 0, stream>>>(z, h1, Wf1p, Wf2p, W1c, bf1, bf2, out);
}

// Round 2
// 305.956 us; speedup vs baseline: 1.3738x; 1.3738x over previous
//
#include <hip/hip_runtime.h>

// GeneralizedHamiltonianDynamics: bf16 MFMA pipeline
// B=32768, DIN=64, HID=1024
// K0: pack weights bf16 (B-pack layout Bp[n][k])
// K1: h1 = tanh(z@W1+b1)            -> ws (bf16)
// K2: gpre2 = W3*(1-tanh^2(h1@W2+b2)) -> ws (bf16)   [256^2 8-wave pipelined GEMM]
// K3: gpre1 = (gpre2@W2^T)*(1-h1^2) -> in-place over h1 (bf16)  [same GEMM]
// K4: out = symplectic(gpre1@W1^T) + tanh(z@Wf1+bf1)@Wf2 + bf2  (fp32)

typedef __attribute__((ext_vector_type(8))) short s16x8;
typedef __attribute__((ext_vector_type(4))) float f32x4;
typedef unsigned short u16;

#define DEVFN static __device__ __forceinline__

constexpr int DIN = 64;
constexpr int HID = 1024;

DEVFN u16 f2bf(float f) {
  unsigned u = __builtin_bit_cast(unsigned, f);
  u += 0x7fffu + ((u >> 16) & 1u);   // round-to-nearest-even
  return (u16)(u >> 16);
}
DEVFN float bf2f(u16 h) {
  unsigned u = ((unsigned)h) << 16;
  return __builtin_bit_cast(float, u);
}
DEVFN float fast_tanh(float x) {
  float e = __builtin_amdgcn_exp2f(x * 2.8853900817779268f);
  return 1.0f - 2.0f * __builtin_amdgcn_rcpf(e + 1.0f);
}
DEVFN f32x4 mfma16(s16x8 a, s16x8 b, f32x4 c) {
  return __builtin_amdgcn_mfma_f32_16x16x32_bf16(a, b, c, 0, 0, 0);
}

#define GLOAD16(g, l) __builtin_amdgcn_global_load_lds( \
    (const __attribute__((address_space(1))) unsigned int*)(const void*)(g), \
    (__attribute__((address_space(3))) unsigned int*)(void*)(l), 16, 0, 0)

// ---------------- K0: weight prep ----------------
__global__ __launch_bounds__(256) void k0_prep(
    const float* W1, const float* W2, const float* Wf1, const float* Wf2,
    u16* W1p, u16* Wf1p, u16* W2tp, u16* W2c, u16* W1c, u16* Wf2p) {
  int id = blockIdx.x * 256 + threadIdx.x;  // grid covers 1048576
  {
    int n = id >> 10, k = id & 1023;
    W2tp[id] = f2bf(W2[k * HID + n]);
    W2c[id]  = f2bf(W2[id]);
  }
  if (id < 65536) {
    int n = id >> 6, k = id & 63;          // n<1024, k<64
    W1p[id]  = f2bf(W1[k * HID + n]);
    Wf1p[id] = f2bf(Wf1[k * HID + n]);
    W1c[id]  = f2bf(W1[id]);
    int n2 = id >> 10, k2 = id & 1023;     // n2<64, k2<1024
    Wf2p[id] = f2bf(Wf2[k2 * DIN + n2]);
  }
}

// ---------------- K1: h1 = tanh(z@W1 + b1) ----------------
__global__ __launch_bounds__(256) void k1_h1(const float* z, const u16* W1p,
                                             const float* b1, u16* h1) {
  __shared__ __align__(16) u16 zl[64 * 72];
  const int tid = threadIdx.x;
  const int lane = tid & 63, w = tid >> 6;
  const int nb = blockIdx.x & 7, mb = blockIdx.x >> 3;
  const size_t m0 = (size_t)mb * 64;
  const int n0 = nb * 128;
#pragma unroll
  for (int c = 0; c < 4; ++c) {
    int i4 = c * 256 + tid;
    int row = i4 >> 4, col4 = (i4 & 15) * 4;
    f32x4 v = *reinterpret_cast<const f32x4*>(z + (m0 + row) * DIN + col4);
    u16* d = zl + row * 72 + col4;
    d[0] = f2bf(v[0]); d[1] = f2bf(v[1]); d[2] = f2bf(v[2]); d[3] = f2bf(v[3]);
  }
  __syncthreads();
  f32x4 acc[8] = {};
#pragma unroll
  for (int kk = 0; kk < 2; ++kk) {
    const int karr = kk * 32 + ((lane >> 4) << 3);
    s16x8 a = *reinterpret_cast<const s16x8*>(zl + (16 * w + (lane & 15)) * 72 + karr);
#pragma unroll
    for (int fn = 0; fn < 8; ++fn) {
      int n = n0 + fn * 16 + (lane & 15);
      s16x8 b = *reinterpret_cast<const s16x8*>(W1p + (size_t)n * 64 + karr);
      acc[fn] = mfma16(a, b, acc[fn]);
    }
  }
#pragma unroll
  for (int fn = 0; fn < 8; ++fn) {
    int n = n0 + fn * 16 + (lane & 15);
    float bias = b1[n];
#pragma unroll
    for (int j = 0; j < 4; ++j) {
      size_t m = m0 + 16 * w + ((lane >> 4) << 2) + j;
      h1[m * HID + n] = f2bf(fast_tanh(acc[fn][j] + bias));
    }
  }
}

// ---------------- K2/K3: 256x256-tile deep-pipelined GEMM ----------------
// 8 waves (2M x 4N), BK=64, double-buffered 128KB LDS, counted vmcnt,
// XOR-swizzled LDS (inverse-swizzled global source for global_load_lds).
// MODE 0: out = bf16( W3[n] * (1 - tanh^2(A@Bp^T + b2[n])) )
// MODE 1: out = bf16( (A@Bp^T) * (1 - h1[m][n]^2) )   (in-place over h1)
template <int MODE>
__global__ __launch_bounds__(512, 2) void k23_gemm(
    const u16* __restrict__ A, const u16* __restrict__ Bp,
    const float* __restrict__ b2, const float* __restrict__ W3,
    const u16* __restrict__ h1in, u16* __restrict__ outb) {
  extern __shared__ u16 lds[];  // 2 bufs x (A[256][64] + B[256][64]) = 65536 u16
  const int tid = threadIdx.x;
  const int lane = tid & 63, w = tid >> 6;
  const int wr = w >> 2, wc = w & 3;
  // XCD-aware: 512 blocks, 8 XCDs, 64/XCD; within XCD nb fastest (4nb x 16mb)
  const int xcd = blockIdx.x & 7, local = blockIdx.x >> 3;
  const size_t m0 = (size_t)(xcd * 16 + (local >> 2)) * 256;
  const int n0 = (local & 3) * 256;

  // staging: 4 GLOAD16 per panel per thread; source pre-swizzled (rule #21)
  const u16* gpa[4]; const u16* gpb[4]; int lo[4];
#pragma unroll
  for (int c = 0; c < 4; ++c) {
    int idx = c * 512 + tid, row = idx >> 3, cg = idx & 7;
    int sc = (cg ^ (row & 7)) << 3;
    gpa[c] = A + (m0 + row) * 1024 + sc;
    gpb[c] = Bp + (size_t)(n0 + row) * 1024 + sc;
    lo[c] = idx * 8;
  }
#define STAGE_A(B_, T_) { _Pragma("unroll") for (int c = 0; c < 4; ++c) \
    GLOAD16(gpa[c] + (T_) * 64, lds + (B_) * 32768 + lo[c]); }
#define STAGE_B(B_, T_) { _Pragma("unroll") for (int c = 0; c < 4; ++c) \
    GLOAD16(gpb[c] + (T_) * 64, lds + (B_) * 32768 + 16384 + lo[c]); }

  const int swz = (lane & 7) << 3;  // element-space XOR of 16B-chunk bits
  int aoff[8], boff[4];
#pragma unroll
  for (int i = 0; i < 8; ++i)
    aoff[i] = (wr * 128 + i * 16 + (lane & 15)) * 64 + ((lane >> 4) << 3);
#pragma unroll
  for (int j = 0; j < 4; ++j)
    boff[j] = (wc * 64 + j * 16 + (lane & 15)) * 64 + ((lane >> 4) << 3);

  f32x4 acc[8][4] = {};

#define PHASE(B_, KK_) { \
    s16x8 af[8], bf[4]; \
    _Pragma("unroll") for (int i = 0; i < 8; ++i) \
      af[i] = *reinterpret_cast<const s16x8*>(lds + (B_) * 32768 + ((aoff[i] + (KK_) * 32) ^ swz)); \
    _Pragma("unroll") for (int j = 0; j < 4; ++j) \
      bf[j] = *reinterpret_cast<const s16x8*>(lds + (B_) * 32768 + 16384 + ((boff[j] + (KK_) * 32) ^ swz)); \
    __builtin_amdgcn_s_setprio(1); \
    _Pragma("unroll") for (int i = 0; i < 8; ++i) { \
      _Pragma("unroll") for (int j = 0; j < 4; ++j) \
        acc[i][j] = mfma16(af[i], bf[j], acc[i][j]); } \
    __builtin_amdgcn_s_setprio(0); }

  STAGE_A(0, 0); STAGE_B(0, 0);          // 8 loads in flight
  for (int t = 0; t < 15; ++t) {
    const int cur = t & 1, nxt = cur ^ 1;
    STAGE_A(nxt, t + 1);                 // 12 in flight
    asm volatile("s_waitcnt vmcnt(4)" ::: "memory");  // tile t fully staged
    __builtin_amdgcn_s_barrier();
    asm volatile("" ::: "memory");
    PHASE(cur, 0);
    STAGE_B(nxt, t + 1);                 // 8 in flight
    PHASE(cur, 1);
    asm volatile("" ::: "memory");
    __builtin_amdgcn_s_barrier();        // all waves done reading buf[cur]
    asm volatile("" ::: "memory");
  }
  asm volatile("s_waitcnt vmcnt(0)" ::: "memory");
  __builtin_amdgcn_s_barrier();
  asm volatile("" ::: "memory");
  PHASE(1, 0);
  PHASE(1, 1);
  asm volatile("" ::: "memory");
  __builtin_amdgcn_s_barrier();          // LDS now reusable for epilogue
  asm volatile("" ::: "memory");

  // Epilogue: repack through wave-private 16KB LDS region -> coalesced 16B stores
  const int wbase = w * 8192;
  float b2v[4], w3v[4];
  if (MODE == 0) {
#pragma unroll
    for (int j = 0; j < 4; ++j) {
      int n = n0 + wc * 64 + j * 16 + (lane & 15);
      b2v[j] = b2[n]; w3v[j] = W3[n];
    }
  }
#pragma unroll
  for (int h = 0; h < 2; ++h) {
    if (h == 1) asm volatile("s_waitcnt lgkmcnt(0)" ::: "memory");
#pragma unroll
    for (int ip = 0; ip < 4; ++ip) {
#pragma unroll
      for (int j = 0; j < 4; ++j) {
#pragma unroll
        for (int r = 0; r < 4; ++r) {
          float v = acc[h * 4 + ip][j][r];
          u16 o;
          if (MODE == 0) {
            float tt = fast_tanh(v + b2v[j]);
            o = f2bf(w3v[j] * (1.f - tt * tt));
          } else {
            o = f2bf(v);
          }
          int lr = ip * 16 + ((lane >> 4) << 2) + r;
          lds[wbase + lr * 64 + j * 16 + (lane & 15)] = o;
        }
      }
    }
#pragma unroll
    for (int r8 = 0; r8 < 8; ++r8) {
      int lr = r8 * 8 + (lane >> 3), c8 = (lane & 7) * 8;
      s16x8 vv = *reinterpret_cast<const s16x8*>(lds + wbase + lr * 64 + c8);
      size_t grow = m0 + wr * 128 + h * 64 + lr;
      int gcol = n0 + wc * 64 + c8;
      if (MODE == 1) {
        s16x8 hh = *reinterpret_cast<const s16x8*>(h1in + grow * 1024 + gcol);
#pragma unroll
        for (int e = 0; e < 8; ++e) {
          float hv = bf2f((u16)hh[e]);
          vv[e] = (short)f2bf(bf2f((u16)vv[e]) * (1.f - hv * hv));
        }
      }
      *reinterpret_cast<s16x8*>(outb + grow * 1024 + gcol) = vv;
    }
  }
#undef STAGE_A
#undef STAGE_B
#undef PHASE
}

// ---------------- K4: final fused kernel ----------------
__global__ __launch_bounds__(256) void k4_final(
    const float* z, const u16* gp1, const u16* Wf1p, const u16* Wf2p,
    const u16* W1c, const float* bf1, const float* bf2, float* out) {
  __shared__ __align__(16) u16 zl[64 * 72];
  __shared__ __align__(16) u16 f1l[64 * 72];
  __shared__ __align__(16) u16 gl[64 * 64];
  const int tid = threadIdx.x;
  const int lane = tid & 63, w = tid >> 6;
  const size_t m0 = (size_t)blockIdx.x * 64;
#pragma unroll
  for (int c = 0; c < 4; ++c) {
    int i4 = c * 256 + tid;
    int row = i4 >> 4, col4 = (i4 & 15) * 4;
    f32x4 v = *reinterpret_cast<const f32x4*>(z + (m0 + row) * DIN + col4);
    u16* d = zl + row * 72 + col4;
    d[0] = f2bf(v[0]); d[1] = f2bf(v[1]); d[2] = f2bf(v[2]); d[3] = f2bf(v[3]);
  }
  __syncthreads();
  f32x4 facc[4] = {};
  f32x4 hacc[4] = {};
  for (int kc = 0; kc < 16; ++kc) {
    const int kbase = kc * 64;
    f32x4 pacc[4] = {};
#pragma unroll
    for (int kk = 0; kk < 2; ++kk) {
      const int karr = kk * 32 + ((lane >> 4) << 3);
      s16x8 a = *reinterpret_cast<const s16x8*>(zl + (16 * w + (lane & 15)) * 72 + karr);
#pragma unroll
      for (int fn = 0; fn < 4; ++fn) {
        int n = kbase + fn * 16 + (lane & 15);
        s16x8 b = *reinterpret_cast<const s16x8*>(Wf1p + (size_t)n * 64 + karr);
        pacc[fn] = mfma16(a, b, pacc[fn]);
      }
    }
#pragma unroll
    for (int fn = 0; fn < 4; ++fn) {
      int nloc = fn * 16 + (lane & 15);
      float bias = bf1[kbase + nloc];
#pragma unroll
      for (int j = 0; j < 4; ++j) {
        int r = 16 * w + ((lane >> 4) << 2) + j;
        f1l[r * 72 + nloc] = f2bf(fast_tanh(pacc[fn][j] + bias));
      }
    }
    __syncthreads();
#pragma unroll
    for (int c = 0; c < 2; ++c) {
      int idx = c * 256 + tid;
      int row = idx >> 3, k8 = (idx & 7) << 3;
      GLOAD16(gp1 + (m0 + row) * 1024 + kbase + k8, gl + idx * 8);
    }
#pragma unroll
    for (int kk = 0; kk < 2; ++kk) {
      const int karr = kk * 32 + ((lane >> 4) << 3);
      s16x8 af = *reinterpret_cast<const s16x8*>(f1l + (16 * w + (lane & 15)) * 72 + karr);
#pragma unroll
      for (int fn = 0; fn < 4; ++fn) {
        int n = fn * 16 + (lane & 15);
        s16x8 b = *reinterpret_cast<const s16x8*>(Wf2p + (size_t)n * 1024 + kbase + karr);
        facc[fn] = mfma16(af, b, facc[fn]);
      }
    }
    __syncthreads();
#pragma unroll
    for (int kk = 0; kk < 2; ++kk) {
      const int karr = kk * 32 + ((lane >> 4) << 3);
      s16x8 ag = *reinterpret_cast<const s16x8*>(gl + (16 * w + (lane & 15)) * 64 + karr);
#pragma unroll
      for (int fn = 0; fn < 4; ++fn) {
        int n = fn * 16 + (lane & 15);
        s16x8 b = *reinterpret_cast<const s16x8*>(W1c + (size_t)n * 1024 + kbase + karr);
        hacc[fn] = mfma16(ag, b, hacc[fn]);
      }
    }
  }
#pragma unroll
  for (int fn = 0; fn < 4; ++fn) {
    int n = fn * 16 + (lane & 15);
    float bias = bf2[n];
    float sgn = (fn < 2) ? 1.f : -1.f;
#pragma unroll
    for (int j = 0; j < 4; ++j) {
      size_t m = m0 + 16 * w + ((lane >> 4) << 2) + j;
      out[m * DIN + n] = facc[fn][j] + bias + sgn * hacc[(fn + 2) & 3][j];
    }
  }
}

extern "C" void kernel_launch(void* const* d_in, const int* in_sizes, int n_in,
                              void* d_out, int out_size, void* d_ws, size_t ws_size,
                              hipStream_t stream) {
  const float* z   = (const float*)d_in[0];
  const float* W1  = (const float*)d_in[1];
  const float* b1  = (const float*)d_in[2];
  const float* W2  = (const float*)d_in[3];
  const float* b2  = (const float*)d_in[4];
  const float* W3  = (const float*)d_in[5];
  const float* Wf1 = (const float*)d_in[7];
  const float* bf1 = (const float*)d_in[8];
  const float* Wf2 = (const float*)d_in[9];
  const float* bf2 = (const float*)d_in[10];

  char* ws = (char*)d_ws;
  u16* W1p  = (u16*)(ws + 0);          // 128KB
  u16* Wf1p = (u16*)(ws + 131072);     // 128KB
  u16* W2tp = (u16*)(ws + 262144);     // 2MB
  u16* W2c  = (u16*)(ws + 2359296);    // 2MB
  u16* W1c  = (u16*)(ws + 4456448);    // 128KB
  u16* Wf2p = (u16*)(ws + 4587520);    // 128KB
  u16* h1   = (u16*)(ws + 4718592);    // 64MB (becomes gpre1 in-place after K3)
  u16* gp2  = (u16*)(ws + 4718592 + 67108864);  // 64MB
  float* out = (float*)d_out;

  k0_prep<<<4096, 256, 0, stream>>>(W1, W2, Wf1, Wf2, W1p, Wf1p, W2tp, W2c, W1c, Wf2p);
  k1_h1<<<4096, 256, 0, stream>>>(z, W1p, b1, h1);
  k23_gemm<0><<<512, 512, 131072, stream>>>(h1, W2tp, b2, W3, nullptr, gp2);
  k23_gemm<1><<<512, 512, 131072, stream>>>(gp2, W2c, nullptr, nullptr, h1, h1);
  k4_final<<<512, 256, 0, stream>>>(z, h1, Wf1p, Wf2p, W1c, bf1, bf2, out);
}

// Round 3
// 287.105 us; speedup vs baseline: 1.4640x; 1.0657x over previous
//
#include <hip/hip_runtime.h>

// GeneralizedHamiltonianDynamics: bf16 MFMA pipeline
// B=32768, DIN=64, HID=1024
// K0: pack weights bf16 (B-pack layout Bp[n][k])
// K1: h1 = tanh(z@W1+b1)            -> ws (bf16)
// K2: gpre2 = W3*(1-tanh^2(h1@W2+b2)) -> ws (bf16)   [256^2 8-wave pipelined GEMM]
// K3: gpre1 = (gpre2@W2^T)*(1-h1^2) -> in-place over h1 (bf16)  [same GEMM]
// K4: out = symplectic(gpre1@W1^T) + tanh(z@Wf1+bf1)@Wf2 + bf2  (fp32)
//     -> barrier-free per-wave structure, K-split x2, one LDS reduce

typedef __attribute__((ext_vector_type(8))) short s16x8;
typedef __attribute__((ext_vector_type(4))) float f32x4;
typedef unsigned short u16;

#define DEVFN static __device__ __forceinline__

constexpr int DIN = 64;
constexpr int HID = 1024;

DEVFN u16 f2bf(float f) {
  unsigned u = __builtin_bit_cast(unsigned, f);
  u += 0x7fffu + ((u >> 16) & 1u);   // round-to-nearest-even
  return (u16)(u >> 16);
}
DEVFN float bf2f(u16 h) {
  unsigned u = ((unsigned)h) << 16;
  return __builtin_bit_cast(float, u);
}
DEVFN float fast_tanh(float x) {
  float e = __builtin_amdgcn_exp2f(x * 2.8853900817779268f);
  return 1.0f - 2.0f * __builtin_amdgcn_rcpf(e + 1.0f);
}
DEVFN f32x4 mfma16(s16x8 a, s16x8 b, f32x4 c) {
  return __builtin_amdgcn_mfma_f32_16x16x32_bf16(a, b, c, 0, 0, 0);
}

#define GLOAD16(g, l) __builtin_amdgcn_global_load_lds( \
    (const __attribute__((address_space(1))) unsigned int*)(const void*)(g), \
    (__attribute__((address_space(3))) unsigned int*)(void*)(l), 16, 0, 0)

// ---------------- K0: weight prep ----------------
__global__ __launch_bounds__(256) void k0_prep(
    const float* W1, const float* W2, const float* Wf1, const float* Wf2,
    u16* W1p, u16* Wf1p, u16* W2tp, u16* W2c, u16* W1c, u16* Wf2p) {
  int id = blockIdx.x * 256 + threadIdx.x;  // grid covers 1048576
  {
    int n = id >> 10, k = id & 1023;
    W2tp[id] = f2bf(W2[k * HID + n]);
    W2c[id]  = f2bf(W2[id]);
  }
  if (id < 65536) {
    int n = id >> 6, k = id & 63;          // n<1024, k<64
    W1p[id]  = f2bf(W1[k * HID + n]);
    Wf1p[id] = f2bf(Wf1[k * HID + n]);
    W1c[id]  = f2bf(W1[id]);
    int n2 = id >> 10, k2 = id & 1023;     // n2<64, k2<1024
    Wf2p[id] = f2bf(Wf2[k2 * DIN + n2]);
  }
}

// ---------------- K1: h1 = tanh(z@W1 + b1) ----------------
__global__ __launch_bounds__(256) void k1_h1(const float* z, const u16* W1p,
                                             const float* b1, u16* h1) {
  __shared__ __align__(16) u16 zl[64 * 72];
  const int tid = threadIdx.x;
  const int lane = tid & 63, w = tid >> 6;
  const int nb = blockIdx.x & 7, mb = blockIdx.x >> 3;
  const size_t m0 = (size_t)mb * 64;
  const int n0 = nb * 128;
#pragma unroll
  for (int c = 0; c < 4; ++c) {
    int i4 = c * 256 + tid;
    int row = i4 >> 4, col4 = (i4 & 15) * 4;
    f32x4 v = *reinterpret_cast<const f32x4*>(z + (m0 + row) * DIN + col4);
    u16* d = zl + row * 72 + col4;
    d[0] = f2bf(v[0]); d[1] = f2bf(v[1]); d[2] = f2bf(v[2]); d[3] = f2bf(v[3]);
  }
  __syncthreads();
  f32x4 acc[8] = {};
#pragma unroll
  for (int kk = 0; kk < 2; ++kk) {
    const int karr = kk * 32 + ((lane >> 4) << 3);
    s16x8 a = *reinterpret_cast<const s16x8*>(zl + (16 * w + (lane & 15)) * 72 + karr);
#pragma unroll
    for (int fn = 0; fn < 8; ++fn) {
      int n = n0 + fn * 16 + (lane & 15);
      s16x8 b = *reinterpret_cast<const s16x8*>(W1p + (size_t)n * 64 + karr);
      acc[fn] = mfma16(a, b, acc[fn]);
    }
  }
#pragma unroll
  for (int fn = 0; fn < 8; ++fn) {
    int n = n0 + fn * 16 + (lane & 15);
    float bias = b1[n];
#pragma unroll
    for (int j = 0; j < 4; ++j) {
      size_t m = m0 + 16 * w + ((lane >> 4) << 2) + j;
      h1[m * HID + n] = f2bf(fast_tanh(acc[fn][j] + bias));
    }
  }
}

// ---------------- K2/K3: 256x256-tile deep-pipelined GEMM ----------------
template <int MODE>
__global__ __launch_bounds__(512, 2) void k23_gemm(
    const u16* __restrict__ A, const u16* __restrict__ Bp,
    const float* __restrict__ b2, const float* __restrict__ W3,
    const u16* __restrict__ h1in, u16* __restrict__ outb) {
  extern __shared__ u16 lds[];  // 2 bufs x (A[256][64] + B[256][64]) = 65536 u16
  const int tid = threadIdx.x;
  const int lane = tid & 63, w = tid >> 6;
  const int wr = w >> 2, wc = w & 3;
  const int xcd = blockIdx.x & 7, local = blockIdx.x >> 3;
  const size_t m0 = (size_t)(xcd * 16 + (local >> 2)) * 256;
  const int n0 = (local & 3) * 256;

  const u16* gpa[4]; const u16* gpb[4]; int lo[4];
#pragma unroll
  for (int c = 0; c < 4; ++c) {
    int idx = c * 512 + tid, row = idx >> 3, cg = idx & 7;
    int sc = (cg ^ (row & 7)) << 3;
    gpa[c] = A + (m0 + row) * 1024 + sc;
    gpb[c] = Bp + (size_t)(n0 + row) * 1024 + sc;
    lo[c] = idx * 8;
  }
#define STAGE_A(B_, T_) { _Pragma("unroll") for (int c = 0; c < 4; ++c) \
    GLOAD16(gpa[c] + (T_) * 64, lds + (B_) * 32768 + lo[c]); }
#define STAGE_B(B_, T_) { _Pragma("unroll") for (int c = 0; c < 4; ++c) \
    GLOAD16(gpb[c] + (T_) * 64, lds + (B_) * 32768 + 16384 + lo[c]); }

  const int swz = (lane & 7) << 3;
  int aoff[8], boff[4];
#pragma unroll
  for (int i = 0; i < 8; ++i)
    aoff[i] = (wr * 128 + i * 16 + (lane & 15)) * 64 + ((lane >> 4) << 3);
#pragma unroll
  for (int j = 0; j < 4; ++j)
    boff[j] = (wc * 64 + j * 16 + (lane & 15)) * 64 + ((lane >> 4) << 3);

  f32x4 acc[8][4] = {};

#define PHASE(B_, KK_) { \
    s16x8 af[8], bf[4]; \
    _Pragma("unroll") for (int i = 0; i < 8; ++i) \
      af[i] = *reinterpret_cast<const s16x8*>(lds + (B_) * 32768 + ((aoff[i] + (KK_) * 32) ^ swz)); \
    _Pragma("unroll") for (int j = 0; j < 4; ++j) \
      bf[j] = *reinterpret_cast<const s16x8*>(lds + (B_) * 32768 + 16384 + ((boff[j] + (KK_) * 32) ^ swz)); \
    __builtin_amdgcn_s_setprio(1); \
    _Pragma("unroll") for (int i = 0; i < 8; ++i) { \
      _Pragma("unroll") for (int j = 0; j < 4; ++j) \
        acc[i][j] = mfma16(af[i], bf[j], acc[i][j]); } \
    __builtin_amdgcn_s_setprio(0); }

  STAGE_A(0, 0); STAGE_B(0, 0);
  for (int t = 0; t < 15; ++t) {
    const int cur = t & 1, nxt = cur ^ 1;
    STAGE_A(nxt, t + 1);
    asm volatile("s_waitcnt vmcnt(4)" ::: "memory");
    __builtin_amdgcn_s_barrier();
    asm volatile("" ::: "memory");
    PHASE(cur, 0);
    STAGE_B(nxt, t + 1);
    PHASE(cur, 1);
    asm volatile("" ::: "memory");
    __builtin_amdgcn_s_barrier();
    asm volatile("" ::: "memory");
  }
  asm volatile("s_waitcnt vmcnt(0)" ::: "memory");
  __builtin_amdgcn_s_barrier();
  asm volatile("" ::: "memory");
  PHASE(1, 0);
  PHASE(1, 1);
  asm volatile("" ::: "memory");
  __builtin_amdgcn_s_barrier();
  asm volatile("" ::: "memory");

  const int wbase = w * 8192;
  float b2v[4], w3v[4];
  if (MODE == 0) {
#pragma unroll
    for (int j = 0; j < 4; ++j) {
      int n = n0 + wc * 64 + j * 16 + (lane & 15);
      b2v[j] = b2[n]; w3v[j] = W3[n];
    }
  }
#pragma unroll
  for (int h = 0; h < 2; ++h) {
    if (h == 1) asm volatile("s_waitcnt lgkmcnt(0)" ::: "memory");
#pragma unroll
    for (int ip = 0; ip < 4; ++ip) {
#pragma unroll
      for (int j = 0; j < 4; ++j) {
#pragma unroll
        for (int r = 0; r < 4; ++r) {
          float v = acc[h * 4 + ip][j][r];
          u16 o;
          if (MODE == 0) {
            float tt = fast_tanh(v + b2v[j]);
            o = f2bf(w3v[j] * (1.f - tt * tt));
          } else {
            o = f2bf(v);
          }
          int lr = ip * 16 + ((lane >> 4) << 2) + r;
          lds[wbase + lr * 64 + j * 16 + (lane & 15)] = o;
        }
      }
    }
#pragma unroll
    for (int r8 = 0; r8 < 8; ++r8) {
      int lr = r8 * 8 + (lane >> 3), c8 = (lane & 7) * 8;
      s16x8 vv = *reinterpret_cast<const s16x8*>(lds + wbase + lr * 64 + c8);
      size_t grow = m0 + wr * 128 + h * 64 + lr;
      int gcol = n0 + wc * 64 + c8;
      if (MODE == 1) {
        s16x8 hh = *reinterpret_cast<const s16x8*>(h1in + grow * 1024 + gcol);
#pragma unroll
        for (int e = 0; e < 8; ++e) {
          float hv = bf2f((u16)hh[e]);
          vv[e] = (short)f2bf(bf2f((u16)vv[e]) * (1.f - hv * hv));
        }
      }
      *reinterpret_cast<s16x8*>(outb + grow * 1024 + gcol) = vv;
    }
  }
#undef STAGE_A
#undef STAGE_B
#undef PHASE
}

// ---------------- K4: barrier-free fused finale ----------------
// Block = 256 threads = 4 waves. Waves (0,1) own rows [0,16); (2,3) own [16,32)
// of a 32-row tile. Within a pair, wave half=w&1 handles K-chunks half*8..+8.
// All operands loaded global->reg (weights L1/L2-hot); only LDS use is the
// wave-private XOR-swizzled f1 transpose + one end-of-kernel pair reduction.
__global__ __launch_bounds__(256) void k4_final(
    const float* __restrict__ z, const u16* __restrict__ gp1,
    const u16* __restrict__ Wf1p, const u16* __restrict__ Wf2p,
    const u16* __restrict__ W1c, const float* __restrict__ bf1,
    const float* __restrict__ bf2, float* __restrict__ out) {
  __shared__ u16 f1l[4][1024];        // per-wave [16][64] u16, XOR-swizzled
  __shared__ float red[2][64][33];    // pair-reduction, stride-33 (conflict-free)
  const int tid = threadIdx.x;
  const int lane = tid & 63, w = tid >> 6;
  const int wpair = w >> 1, half = w & 1;
  const int lr = lane & 15, g = lane >> 4;
  const size_t m0 = (size_t)blockIdx.x * 32 + wpair * 16;  // wave's 16 rows
  u16* fl = f1l[w];

  // z A-frags (K=64): hoisted, direct global fp32 -> bf16
  s16x8 za[2];
#pragma unroll
  for (int kk = 0; kk < 2; ++kk) {
    const float* src = z + (m0 + lr) * DIN + kk * 32 + g * 8;
    f32x4 v0 = *reinterpret_cast<const f32x4*>(src);
    f32x4 v1 = *reinterpret_cast<const f32x4*>(src + 4);
    s16x8 t;
    t[0] = (short)f2bf(v0[0]); t[1] = (short)f2bf(v0[1]);
    t[2] = (short)f2bf(v0[2]); t[3] = (short)f2bf(v0[3]);
    t[4] = (short)f2bf(v1[0]); t[5] = (short)f2bf(v1[1]);
    t[6] = (short)f2bf(v1[2]); t[7] = (short)f2bf(v1[3]);
    za[kk] = t;
  }

  f32x4 facc[4] = {};
  f32x4 hacc[4] = {};
  const int kc_lo = half * 8, kc_hi = kc_lo + 8;
#pragma unroll 2
  for (int kc = kc_lo; kc < kc_hi; ++kc) {
    const int kbase = kc * 64;
    // 1) pacc = z @ Wf1 chunk (f1 pre-activation, cols kbase..kbase+63)
    f32x4 pacc[4] = {};
#pragma unroll
    for (int kk = 0; kk < 2; ++kk) {
#pragma unroll
      for (int fn = 0; fn < 4; ++fn) {
        int n = kbase + fn * 16 + lr;
        s16x8 b = *reinterpret_cast<const s16x8*>(Wf1p + (size_t)n * 64 + kk * 32 + g * 8);
        pacc[fn] = mfma16(za[kk], b, pacc[fn]);
      }
    }
    // 2) f1 = tanh(pacc + bf1) -> wave-private swizzled LDS (C-layout -> A-layout)
#pragma unroll
    for (int fn = 0; fn < 4; ++fn) {
      float bias = bf1[kbase + fn * 16 + lr];
#pragma unroll
      for (int j = 0; j < 4; ++j) {
        int r = g * 4 + j;
        int c = fn * 16 + lr;
        fl[r * 64 + (c ^ ((r & 7) << 3))] = f2bf(fast_tanh(pacc[fn][j] + bias));
      }
    }
    asm volatile("s_waitcnt lgkmcnt(0)" ::: "memory");
    __builtin_amdgcn_sched_barrier(0);
    // 3) facc += f1 @ Wf2 chunk
#pragma unroll
    for (int kk = 0; kk < 2; ++kk) {
      int c0 = (kk * 32 + g * 8) ^ ((lr & 7) << 3);
      s16x8 a = *reinterpret_cast<const s16x8*>(fl + lr * 64 + c0);
#pragma unroll
      for (int fn = 0; fn < 4; ++fn) {
        s16x8 b = *reinterpret_cast<const s16x8*>(Wf2p + (size_t)(fn * 16 + lr) * 1024 + kbase + kk * 32 + g * 8);
        facc[fn] = mfma16(a, b, facc[fn]);
      }
    }
    // 4) hacc += gpre1 chunk @ W1^T  (gp1 A-frags direct from global, L3-hot)
#pragma unroll
    for (int kk = 0; kk < 2; ++kk) {
      s16x8 ag = *reinterpret_cast<const s16x8*>(gp1 + (m0 + lr) * 1024 + kbase + kk * 32 + g * 8);
#pragma unroll
      for (int fn = 0; fn < 4; ++fn) {
        s16x8 b = *reinterpret_cast<const s16x8*>(W1c + (size_t)(fn * 16 + lr) * 1024 + kbase + kk * 32 + g * 8);
        hacc[fn] = mfma16(ag, b, hacc[fn]);
      }
    }
  }

  // pair reduction: half==1 writes partials, half==0 adds + stores
  if (half == 1) {
#pragma unroll
    for (int fn = 0; fn < 4; ++fn)
#pragma unroll
      for (int j = 0; j < 4; ++j) {
        red[wpair][lane][fn * 4 + j] = facc[fn][j];
        red[wpair][lane][16 + fn * 4 + j] = hacc[fn][j];
      }
  }
  __syncthreads();
  if (half == 0) {
#pragma unroll
    for (int fn = 0; fn < 4; ++fn)
#pragma unroll
      for (int j = 0; j < 4; ++j) {
        facc[fn][j] += red[wpair][lane][fn * 4 + j];
        hacc[fn][j] += red[wpair][lane][16 + fn * 4 + j];
      }
#pragma unroll
    for (int fn = 0; fn < 4; ++fn) {
      int n = fn * 16 + lr;
      float bias = bf2[n];
      float sgn = (fn < 2) ? 1.f : -1.f;
#pragma unroll
      for (int j = 0; j < 4; ++j) {
        size_t m = m0 + g * 4 + j;
        out[m * DIN + n] = facc[fn][j] + bias + sgn * hacc[(fn + 2) & 3][j];
      }
    }
  }
}

extern "C" void kernel_launch(void* const* d_in, const int* in_sizes, int n_in,
                              void* d_out, int out_size, void* d_ws, size_t ws_size,
                              hipStream_t stream) {
  const float* z   = (const float*)d_in[0];
  const float* W1  = (const float*)d_in[1];
  const float* b1  = (const float*)d_in[2];
  const float* W2  = (const float*)d_in[3];
  const float* b2  = (const float*)d_in[4];
  const float* W3  = (const float*)d_in[5];
  const float* Wf1 = (const float*)d_in[7];
  const float* bf1 = (const float*)d_in[8];
  const float* Wf2 = (const float*)d_in[9];
  const float* bf2 = (const float*)d_in[10];

  char* ws = (char*)d_ws;
  u16* W1p  = (u16*)(ws + 0);          // 128KB
  u16* Wf1p = (u16*)(ws + 131072);     // 128KB
  u16* W2tp = (u16*)(ws + 262144);     // 2MB
  u16* W2c  = (u16*)(ws + 2359296);    // 2MB
  u16* W1c  = (u16*)(ws + 4456448);    // 128KB
  u16* Wf2p = (u16*)(ws + 4587520);    // 128KB
  u16* h1   = (u16*)(ws + 4718592);    // 64MB (becomes gpre1 in-place after K3)
  u16* gp2  = (u16*)(ws + 4718592 + 67108864);  // 64MB
  float* out = (float*)d_out;

  k0_prep<<<4096, 256, 0, stream>>>(W1, W2, Wf1, Wf2, W1p, Wf1p, W2tp, W2c, W1c, Wf2p);
  k1_h1<<<4096, 256, 0, stream>>>(z, W1p, b1, h1);
  k23_gemm<0><<<512, 512, 131072, stream>>>(h1, W2tp, b2, W3, nullptr, gp2);
  k23_gemm<1><<<512, 512, 131072, stream>>>(gp2, W2c, nullptr, nullptr, h1, h1);
  k4_final<<<1024, 256, 0, stream>>>(z, h1, Wf1p, Wf2p, W1c, bf1, bf2, out);
}

// Round 4
// 254.192 us; speedup vs baseline: 1.6535x; 1.1295x over previous
//
#include <hip/hip_runtime.h>

// GeneralizedHamiltonianDynamics: bf16 MFMA pipeline
// B=32768, DIN=64, HID=1024
// K0: pack weights bf16 (B-pack layout Bp[n][k]); W1s = symplectic-folded W1
// K1: h1 = tanh(z@W1+b1)            -> ws (bf16)
// K2: gpre2 = W3*(1-tanh^2(h1@W2+b2)) -> ws (bf16)   [256^2 8-wave pipelined GEMM]
// K3: gpre1 = (gpre2@W2^T)*(1-h1^2) -> in-place over h1 (bf16)  [same GEMM]
// K1f: f1 = tanh(z@Wf1+bf1) -> gp2 buffer (free after K3)
// K4: out = [gp1|f1] @ [W1s|Wf2p]^T + bf2   (skinny streaming GEMM, fp32 out)

typedef __attribute__((ext_vector_type(8))) short s16x8;
typedef __attribute__((ext_vector_type(4))) float f32x4;
typedef unsigned short u16;

#define DEVFN static __device__ __forceinline__

constexpr int DIN = 64;
constexpr int HID = 1024;

DEVFN u16 f2bf(float f) {
  unsigned u = __builtin_bit_cast(unsigned, f);
  u += 0x7fffu + ((u >> 16) & 1u);   // round-to-nearest-even
  return (u16)(u >> 16);
}
DEVFN float bf2f(u16 h) {
  unsigned u = ((unsigned)h) << 16;
  return __builtin_bit_cast(float, u);
}
DEVFN float fast_tanh(float x) {
  float e = __builtin_amdgcn_exp2f(x * 2.8853900817779268f);
  return 1.0f - 2.0f * __builtin_amdgcn_rcpf(e + 1.0f);
}
DEVFN f32x4 mfma16(s16x8 a, s16x8 b, f32x4 c) {
  return __builtin_amdgcn_mfma_f32_16x16x32_bf16(a, b, c, 0, 0, 0);
}

#define GLOAD16(g, l) __builtin_amdgcn_global_load_lds( \
    (const __attribute__((address_space(1))) unsigned int*)(const void*)(g), \
    (__attribute__((address_space(3))) unsigned int*)(void*)(l), 16, 0, 0)

// ---------------- K0: weight prep ----------------
// W1p [1024][64]  = W1^T    (B-pack for z@W1)
// Wf1p[1024][64]  = Wf1^T   (B-pack for z@Wf1)
// W2tp[1024][1024]= W2^T    (B-pack for h1@W2)
// W2c [1024][1024]= W2      (B-pack for gpre2@W2^T)
// W1s [64][1024]  = sgn(n)*W1[(n+32)&63][k]  (symplectic-folded, for gradH)
// Wf2p[64][1024]  = Wf2^T   (B-pack for f1@Wf2)
__global__ __launch_bounds__(256) void k0_prep(
    const float* W1, const float* W2, const float* Wf1, const float* Wf2,
    u16* W1p, u16* Wf1p, u16* W2tp, u16* W2c, u16* W1s, u16* Wf2p) {
  int id = blockIdx.x * 256 + threadIdx.x;  // grid covers 1048576
  {
    int n = id >> 10, k = id & 1023;
    W2tp[id] = f2bf(W2[k * HID + n]);
    W2c[id]  = f2bf(W2[id]);
  }
  if (id < 65536) {
    int n = id >> 6, k = id & 63;          // n<1024, k<64
    W1p[id]  = f2bf(W1[k * HID + n]);
    Wf1p[id] = f2bf(Wf1[k * HID + n]);
    int nn = id >> 10, kk2 = id & 1023;    // nn<64, kk2<1024
    float s = (nn < 32) ? 1.f : -1.f;
    W1s[id]  = f2bf(s * W1[((nn + 32) & 63) * HID + kk2]);
    Wf2p[id] = f2bf(Wf2[kk2 * DIN + nn]);
  }
}

// ---------------- K1: out = tanh(z@Wp + b) ---------------- (used for h1 AND f1)
__global__ __launch_bounds__(256) void k1_h1(const float* z, const u16* Wp,
                                             const float* b, u16* o) {
  __shared__ __align__(16) u16 zl[64 * 72];
  const int tid = threadIdx.x;
  const int lane = tid & 63, w = tid >> 6;
  const int nb = blockIdx.x & 7, mb = blockIdx.x >> 3;
  const size_t m0 = (size_t)mb * 64;
  const int n0 = nb * 128;
#pragma unroll
  for (int c = 0; c < 4; ++c) {
    int i4 = c * 256 + tid;
    int row = i4 >> 4, col4 = (i4 & 15) * 4;
    f32x4 v = *reinterpret_cast<const f32x4*>(z + (m0 + row) * DIN + col4);
    u16* d = zl + row * 72 + col4;
    d[0] = f2bf(v[0]); d[1] = f2bf(v[1]); d[2] = f2bf(v[2]); d[3] = f2bf(v[3]);
  }
  __syncthreads();
  f32x4 acc[8] = {};
#pragma unroll
  for (int kk = 0; kk < 2; ++kk) {
    const int karr = kk * 32 + ((lane >> 4) << 3);
    s16x8 a = *reinterpret_cast<const s16x8*>(zl + (16 * w + (lane & 15)) * 72 + karr);
#pragma unroll
    for (int fn = 0; fn < 8; ++fn) {
      int n = n0 + fn * 16 + (lane & 15);
      s16x8 bb = *reinterpret_cast<const s16x8*>(Wp + (size_t)n * 64 + karr);
      acc[fn] = mfma16(a, bb, acc[fn]);
    }
  }
#pragma unroll
  for (int fn = 0; fn < 8; ++fn) {
    int n = n0 + fn * 16 + (lane & 15);
    float bias = b[n];
#pragma unroll
    for (int j = 0; j < 4; ++j) {
      size_t m = m0 + 16 * w + ((lane >> 4) << 2) + j;
      o[m * HID + n] = f2bf(fast_tanh(acc[fn][j] + bias));
    }
  }
}

// ---------------- K2/K3: 256x256-tile deep-pipelined GEMM ----------------
template <int MODE>
__global__ __launch_bounds__(512, 2) void k23_gemm(
    const u16* __restrict__ A, const u16* __restrict__ Bp,
    const float* __restrict__ b2, const float* __restrict__ W3,
    const u16* __restrict__ h1in, u16* __restrict__ outb) {
  extern __shared__ u16 lds[];  // 2 bufs x (A[256][64] + B[256][64]) = 65536 u16
  const int tid = threadIdx.x;
  const int lane = tid & 63, w = tid >> 6;
  const int wr = w >> 2, wc = w & 3;
  const int xcd = blockIdx.x & 7, local = blockIdx.x >> 3;
  const size_t m0 = (size_t)(xcd * 16 + (local >> 2)) * 256;
  const int n0 = (local & 3) * 256;

  const u16* gpa[4]; const u16* gpb[4]; int lo[4];
#pragma unroll
  for (int c = 0; c < 4; ++c) {
    int idx = c * 512 + tid, row = idx >> 3, cg = idx & 7;
    int sc = (cg ^ (row & 7)) << 3;
    gpa[c] = A + (m0 + row) * 1024 + sc;
    gpb[c] = Bp + (size_t)(n0 + row) * 1024 + sc;
    lo[c] = idx * 8;
  }
#define STAGE_A(B_, T_) { _Pragma("unroll") for (int c = 0; c < 4; ++c) \
    GLOAD16(gpa[c] + (T_) * 64, lds + (B_) * 32768 + lo[c]); }
#define STAGE_B(B_, T_) { _Pragma("unroll") for (int c = 0; c < 4; ++c) \
    GLOAD16(gpb[c] + (T_) * 64, lds + (B_) * 32768 + 16384 + lo[c]); }

  const int swz = (lane & 7) << 3;
  int aoff[8], boff[4];
#pragma unroll
  for (int i = 0; i < 8; ++i)
    aoff[i] = (wr * 128 + i * 16 + (lane & 15)) * 64 + ((lane >> 4) << 3);
#pragma unroll
  for (int j = 0; j < 4; ++j)
    boff[j] = (wc * 64 + j * 16 + (lane & 15)) * 64 + ((lane >> 4) << 3);

  f32x4 acc[8][4] = {};

#define PHASE(B_, KK_) { \
    s16x8 af[8], bf[4]; \
    _Pragma("unroll") for (int i = 0; i < 8; ++i) \
      af[i] = *reinterpret_cast<const s16x8*>(lds + (B_) * 32768 + ((aoff[i] + (KK_) * 32) ^ swz)); \
    _Pragma("unroll") for (int j = 0; j < 4; ++j) \
      bf[j] = *reinterpret_cast<const s16x8*>(lds + (B_) * 32768 + 16384 + ((boff[j] + (KK_) * 32) ^ swz)); \
    __builtin_amdgcn_s_setprio(1); \
    _Pragma("unroll") for (int i = 0; i < 8; ++i) { \
      _Pragma("unroll") for (int j = 0; j < 4; ++j) \
        acc[i][j] = mfma16(af[i], bf[j], acc[i][j]); } \
    __builtin_amdgcn_s_setprio(0); }

  STAGE_A(0, 0); STAGE_B(0, 0);
  for (int t = 0; t < 15; ++t) {
    const int cur = t & 1, nxt = cur ^ 1;
    STAGE_A(nxt, t + 1);
    asm volatile("s_waitcnt vmcnt(4)" ::: "memory");
    __builtin_amdgcn_s_barrier();
    asm volatile("" ::: "memory");
    PHASE(cur, 0);
    STAGE_B(nxt, t + 1);
    PHASE(cur, 1);
    asm volatile("" ::: "memory");
    __builtin_amdgcn_s_barrier();
    asm volatile("" ::: "memory");
  }
  asm volatile("s_waitcnt vmcnt(0)" ::: "memory");
  __builtin_amdgcn_s_barrier();
  asm volatile("" ::: "memory");
  PHASE(1, 0);
  PHASE(1, 1);
  asm volatile("" ::: "memory");
  __builtin_amdgcn_s_barrier();
  asm volatile("" ::: "memory");

  const int wbase = w * 8192;
  float b2v[4], w3v[4];
  if (MODE == 0) {
#pragma unroll
    for (int j = 0; j < 4; ++j) {
      int n = n0 + wc * 64 + j * 16 + (lane & 15);
      b2v[j] = b2[n]; w3v[j] = W3[n];
    }
  }
#pragma unroll
  for (int h = 0; h < 2; ++h) {
    if (h == 1) asm volatile("s_waitcnt lgkmcnt(0)" ::: "memory");
#pragma unroll
    for (int ip = 0; ip < 4; ++ip) {
#pragma unroll
      for (int j = 0; j < 4; ++j) {
#pragma unroll
        for (int r = 0; r < 4; ++r) {
          float v = acc[h * 4 + ip][j][r];
          u16 o;
          if (MODE == 0) {
            float tt = fast_tanh(v + b2v[j]);
            o = f2bf(w3v[j] * (1.f - tt * tt));
          } else {
            o = f2bf(v);
          }
          int lr = ip * 16 + ((lane >> 4) << 2) + r;
          lds[wbase + lr * 64 + j * 16 + (lane & 15)] = o;
        }
      }
    }
#pragma unroll
    for (int r8 = 0; r8 < 8; ++r8) {
      int lr = r8 * 8 + (lane >> 3), c8 = (lane & 7) * 8;
      s16x8 vv = *reinterpret_cast<const s16x8*>(lds + wbase + lr * 64 + c8);
      size_t grow = m0 + wr * 128 + h * 64 + lr;
      int gcol = n0 + wc * 64 + c8;
      if (MODE == 1) {
        s16x8 hh = *reinterpret_cast<const s16x8*>(h1in + grow * 1024 + gcol);
#pragma unroll
        for (int e = 0; e < 8; ++e) {
          float hv = bf2f((u16)hh[e]);
          vv[e] = (short)f2bf(bf2f((u16)vv[e]) * (1.f - hv * hv));
        }
      }
      *reinterpret_cast<s16x8*>(outb + grow * 1024 + gcol) = vv;
    }
  }
#undef STAGE_A
#undef STAGE_B
#undef PHASE
}

// ---------------- K4: skinny streaming GEMM ----------------
// out[m][n] = sum_{k<2048} Acat[m][k] * Bcat[n][k] + bf2[n]
// Acat = [gp1 | f1] (two 64MB bf16 buffers), Bcat = [W1s | Wf2p] (L2-hot).
// BM=64, BK=64, 32 K-tiles, 4 waves (wave owns 16 rows x all 64 cols).
// Double-buffered LDS via global_load_lds + pre-swizzled source; counted vmcnt.
__global__ __launch_bounds__(256) void k4_gemm(
    const u16* __restrict__ gp1, const u16* __restrict__ f1,
    const u16* __restrict__ W1s, const u16* __restrict__ Wf2p,
    const float* __restrict__ bf2, float* __restrict__ out) {
  __shared__ __align__(16) u16 Ab[2][4096];   // [64 rows][64 k] swizzled
  __shared__ __align__(16) u16 Bb[2][4096];
  const int tid = threadIdx.x;
  const int lane = tid & 63, w = tid >> 6;
  const int lr = lane & 15, g = lane >> 4;
  const size_t m0 = (size_t)blockIdx.x * 64;

  int aoffs[2], boffs[2], lo[2];
#pragma unroll
  for (int c = 0; c < 2; ++c) {
    int idx = c * 256 + tid;          // 0..511 16B-chunks per tile
    int row = idx >> 3, cg = idx & 7;
    aoffs[c] = (int)((m0 + row) * 1024) + ((cg ^ (row & 7)) << 3);
    boffs[c] = row * 1024 + ((cg ^ (row & 7)) << 3);
    lo[c] = idx * 8;
  }
#define K4STAGE(B_, T_) { \
    const u16* ab_ = (T_) < 16 ? gp1 : f1; \
    const u16* bb_ = (T_) < 16 ? W1s : Wf2p; \
    const int ko_ = ((T_) & 15) * 64; \
    _Pragma("unroll") for (int c = 0; c < 2; ++c) { \
      GLOAD16(ab_ + aoffs[c] + ko_, Ab[B_] + lo[c]); \
      GLOAD16(bb_ + boffs[c] + ko_, Bb[B_] + lo[c]); } }

  const int arow = w * 16 + lr;
  int afr[2], bfr[2][4];
#pragma unroll
  for (int kkl = 0; kkl < 2; ++kkl) {
    afr[kkl] = arow * 64 + ((kkl * 32 + g * 8) ^ ((arow & 7) << 3));
#pragma unroll
    for (int fn = 0; fn < 4; ++fn) {
      int br = fn * 16 + lr;
      bfr[kkl][fn] = br * 64 + ((kkl * 32 + g * 8) ^ ((br & 7) << 3));
    }
  }

  f32x4 acc[4] = {};
  K4STAGE(0, 0);
  for (int t = 0; t < 31; ++t) {
    const int cur = t & 1, nxt = cur ^ 1;
    K4STAGE(nxt, t + 1);
    asm volatile("s_waitcnt vmcnt(4)" ::: "memory");
    __builtin_amdgcn_s_barrier();
    asm volatile("" ::: "memory");
#pragma unroll
    for (int kkl = 0; kkl < 2; ++kkl) {
      s16x8 a = *reinterpret_cast<const s16x8*>(Ab[cur] + afr[kkl]);
#pragma unroll
      for (int fn = 0; fn < 4; ++fn) {
        s16x8 b = *reinterpret_cast<const s16x8*>(Bb[cur] + bfr[kkl][fn]);
        acc[fn] = mfma16(a, b, acc[fn]);
      }
    }
    asm volatile("" ::: "memory");
    __builtin_amdgcn_s_barrier();
    asm volatile("" ::: "memory");
  }
  asm volatile("s_waitcnt vmcnt(0)" ::: "memory");
  __builtin_amdgcn_s_barrier();
  asm volatile("" ::: "memory");
#pragma unroll
  for (int kkl = 0; kkl < 2; ++kkl) {
    s16x8 a = *reinterpret_cast<const s16x8*>(Ab[1] + afr[kkl]);
#pragma unroll
    for (int fn = 0; fn < 4; ++fn) {
      s16x8 b = *reinterpret_cast<const s16x8*>(Bb[1] + bfr[kkl][fn]);
      acc[fn] = mfma16(a, b, acc[fn]);
    }
  }
#pragma unroll
  for (int fn = 0; fn < 4; ++fn) {
    int n = fn * 16 + lr;
    float bias = bf2[n];
#pragma unroll
    for (int j = 0; j < 4; ++j) {
      size_t m = m0 + w * 16 + g * 4 + j;
      out[m * DIN + n] = acc[fn][j] + bias;
    }
  }
#undef K4STAGE
}

extern "C" void kernel_launch(void* const* d_in, const int* in_sizes, int n_in,
                              void* d_out, int out_size, void* d_ws, size_t ws_size,
                              hipStream_t stream) {
  const float* z   = (const float*)d_in[0];
  const float* W1  = (const float*)d_in[1];
  const float* b1  = (const float*)d_in[2];
  const float* W2  = (const float*)d_in[3];
  const float* b2  = (const float*)d_in[4];
  const float* W3  = (const float*)d_in[5];
  const float* Wf1 = (const float*)d_in[7];
  const float* bf1 = (const float*)d_in[8];
  const float* Wf2 = (const float*)d_in[9];
  const float* bf2 = (const float*)d_in[10];

  char* ws = (char*)d_ws;
  u16* W1p  = (u16*)(ws + 0);          // 128KB
  u16* Wf1p = (u16*)(ws + 131072);     // 128KB
  u16* W2tp = (u16*)(ws + 262144);     // 2MB
  u16* W2c  = (u16*)(ws + 2359296);    // 2MB
  u16* W1s  = (u16*)(ws + 4456448);    // 128KB (symplectic-folded W1)
  u16* Wf2p = (u16*)(ws + 4587520);    // 128KB
  u16* h1   = (u16*)(ws + 4718592);    // 64MB (becomes gpre1 in-place after K3)
  u16* gp2  = (u16*)(ws + 4718592 + 67108864);  // 64MB (becomes f1 after K1f)
  float* out = (float*)d_out;

  k0_prep<<<4096, 256, 0, stream>>>(W1, W2, Wf1, Wf2, W1p, Wf1p, W2tp, W2c, W1s, Wf2p);
  k1_h1<<<4096, 256, 0, stream>>>(z, W1p, b1, h1);
  k23_gemm<0><<<512, 512, 131072, stream>>>(h1, W2tp, b2, W3, nullptr, gp2);
  k23_gemm<1><<<512, 512, 131072, stream>>>(gp2, W2c, nullptr, nullptr, h1, h1);
  k1_h1<<<4096, 256, 0, stream>>>(z, Wf1p, bf1, gp2);   // f1 -> gp2 buffer
  k4_gemm<<<512, 256, 0, stream>>>(h1, gp2, W1s, Wf2p, bf2, out);
}